// Round 1
// baseline (595.150 us; speedup 1.0000x reference)
//
#include <hip/hip_runtime.h>
#include <hip/hip_bf16.h>
#include <math.h>

// Problem constants
#define B_SZ 32
#define T_SZ 4096
#define A_SZ 128    // ATTN_DIM
#define E_SZ 512    // ENC_DIM
#define D_SZ 1024   // DEC_DIM

// ---------------------------------------------------------------------------
// Kernel 1: pq[b][a] = sum_d query[b][d] * Wq[d][a]; also zero context output.
// grid: (32), block: (128)
// ---------------------------------------------------------------------------
__global__ __launch_bounds__(128) void k_pq(const float* __restrict__ q,
                                            const float* __restrict__ Wq,
                                            float* __restrict__ pq,
                                            float* __restrict__ ctx_out) {
    const int b = blockIdx.x;
    const int a = threadIdx.x;
    __shared__ float ql[D_SZ];
    #pragma unroll
    for (int s = 0; s < D_SZ / 128; ++s)
        ql[s * 128 + a] = q[b * D_SZ + s * 128 + a];
    __syncthreads();
    float acc = 0.f;
    #pragma unroll 8
    for (int d = 0; d < D_SZ; ++d)
        acc += ql[d] * Wq[d * A_SZ + a];
    pq[b * A_SZ + a] = acc;
    // zero the context region of d_out: 32*512 floats = (32*128) threads * 4
    float4 z = make_float4(0.f, 0.f, 0.f, 0.f);
    *(float4*)(ctx_out + ((size_t)b * 128 + a) * 4) = z;
}

// ---------------------------------------------------------------------------
// Kernel 2: scores[b][t] = sum_a tanh(pq[b][a] + (memory[b][t][:] @ Wm)[a]) * v[a]
// Tall-skinny GEMM: block tile [TT=128 t][128 a], thread tile 8x8, K=E=512
// grid: (T/128, B) = (32, 32), block: 256
// ---------------------------------------------------------------------------
#define TT 128
#define EC 32
#define MT_STRIDE 36   // padded row stride (floats) for memT: 16B-aligned, breaks bank aliasing

__global__ __launch_bounds__(256) void k_scores(const float* __restrict__ mem,
                                                const float* __restrict__ Wm,
                                                const float* __restrict__ pq,
                                                const float* __restrict__ v,
                                                float* __restrict__ scores) {
    __shared__ float memT[TT * MT_STRIDE];   // 128*36*4 = 18 KB
    __shared__ float wmT[EC * A_SZ];         // 32*128*4 = 16 KB

    const int b  = blockIdx.y;
    const int t0 = blockIdx.x * TT;
    const int tid = threadIdx.x;
    const int tx = tid & 15;    // a-dim: a = tx*8 + j
    const int ty = tid >> 4;    // t-dim: t = ty + 16*i

    const float* memB = mem + ((size_t)b * T_SZ + t0) * E_SZ;

    float acc[8][8];
    #pragma unroll
    for (int i = 0; i < 8; ++i)
        #pragma unroll
        for (int j = 0; j < 8; ++j) acc[i][j] = 0.f;

    for (int e0 = 0; e0 < E_SZ; e0 += EC) {
        __syncthreads();
        // stage memory tile [128 t][32 e] -> memT (1024 float4, 4 per thread)
        #pragma unroll
        for (int s = 0; s < 4; ++s) {
            int idx = s * 256 + tid;       // 0..1023
            int t   = idx >> 3;            // 0..127
            int e4  = (idx & 7) << 2;      // 0..28
            float4 val = *(const float4*)(memB + (size_t)t * E_SZ + e0 + e4);
            *(float4*)(&memT[t * MT_STRIDE + e4]) = val;
        }
        // stage Wm tile [32 e][128 a] -> wmT (1024 float4, 4 per thread)
        #pragma unroll
        for (int s = 0; s < 4; ++s) {
            int idx = s * 256 + tid;
            int e   = idx >> 5;            // 0..31
            int a4  = (idx & 31) << 2;     // 0..124
            *(float4*)(&wmT[e * A_SZ + a4]) =
                *(const float4*)(Wm + (size_t)(e0 + e) * A_SZ + a4);
        }
        __syncthreads();

        #pragma unroll 1
        for (int e4 = 0; e4 < EC; e4 += 4) {
            float wv[4][8];
            #pragma unroll
            for (int k = 0; k < 4; ++k) {
                *(float4*)&wv[k][0] = *(float4*)&wmT[(e4 + k) * A_SZ + tx * 8];
                *(float4*)&wv[k][4] = *(float4*)&wmT[(e4 + k) * A_SZ + tx * 8 + 4];
            }
            #pragma unroll
            for (int i = 0; i < 8; ++i) {
                float mm[4];
                *(float4*)mm = *(float4*)&memT[(ty + 16 * i) * MT_STRIDE + e4];
                #pragma unroll
                for (int k = 0; k < 4; ++k)
                    #pragma unroll
                    for (int j = 0; j < 8; ++j)
                        acc[i][j] = fmaf(mm[k], wv[k][j], acc[i][j]);
            }
        }
    }

    // epilogue: tanh + v-dot, reduce over a
    float pqr[8], vr[8];
    #pragma unroll
    for (int j = 0; j < 8; ++j) {
        pqr[j] = pq[b * A_SZ + tx * 8 + j];
        vr[j]  = v[tx * 8 + j];
    }
    #pragma unroll
    for (int i = 0; i < 8; ++i) {
        float part = 0.f;
        #pragma unroll
        for (int j = 0; j < 8; ++j)
            part += tanhf(pqr[j] + acc[i][j]) * vr[j];
        // reduce across the 16 tx lanes (same ty) — masks 1,2,4,8 stay in-group
        #pragma unroll
        for (int off = 1; off < 16; off <<= 1)
            part += __shfl_xor(part, off);
        if (tx == 0)
            scores[(size_t)b * T_SZ + t0 + ty + 16 * i] = part;
    }
}

// ---------------------------------------------------------------------------
// Kernel 3: in-place softmax over each row of scores [32][4096]
// grid: (32), block: 256 (each thread: 16 values as 4x float4)
// ---------------------------------------------------------------------------
__global__ __launch_bounds__(256) void k_softmax(float* __restrict__ sc) {
    const int b = blockIdx.x;
    const int tid = threadIdx.x;
    float* row = sc + (size_t)b * T_SZ;

    float4 v4[4];
    float mx = -1e30f;
    #pragma unroll
    for (int s = 0; s < 4; ++s) {
        v4[s] = *(float4*)&row[(s * 256 + tid) * 4];
        mx = fmaxf(mx, fmaxf(fmaxf(v4[s].x, v4[s].y), fmaxf(v4[s].z, v4[s].w)));
    }
    #pragma unroll
    for (int off = 1; off < 64; off <<= 1)
        mx = fmaxf(mx, __shfl_xor(mx, off));
    __shared__ float redm[4], reds[4];
    const int wid = tid >> 6, lane = tid & 63;
    if (lane == 0) redm[wid] = mx;
    __syncthreads();
    mx = fmaxf(fmaxf(redm[0], redm[1]), fmaxf(redm[2], redm[3]));

    float sum = 0.f;
    #pragma unroll
    for (int s = 0; s < 4; ++s) {
        v4[s].x = __expf(v4[s].x - mx);
        v4[s].y = __expf(v4[s].y - mx);
        v4[s].z = __expf(v4[s].z - mx);
        v4[s].w = __expf(v4[s].w - mx);
        sum += v4[s].x + v4[s].y + v4[s].z + v4[s].w;
    }
    #pragma unroll
    for (int off = 1; off < 64; off <<= 1)
        sum += __shfl_xor(sum, off);
    if (lane == 0) reds[wid] = sum;
    __syncthreads();
    const float inv = 1.f / (reds[0] + reds[1] + reds[2] + reds[3]);
    #pragma unroll
    for (int s = 0; s < 4; ++s) {
        v4[s].x *= inv; v4[s].y *= inv; v4[s].z *= inv; v4[s].w *= inv;
        *(float4*)&row[(s * 256 + tid) * 4] = v4[s];
    }
}

// ---------------------------------------------------------------------------
// Kernel 4: context[b][e] += sum_t align[b][t] * memory[b][t][e]
// grid: (16 t-chunks, 32 b), block: 256 (each thread owns 2 e via float2)
// ---------------------------------------------------------------------------
#define CT 256
__global__ __launch_bounds__(256) void k_ctx(const float* __restrict__ mem,
                                             const float* __restrict__ align,
                                             float* __restrict__ ctx) {
    const int b  = blockIdx.y;
    const int t0 = blockIdx.x * CT;
    const int tid = threadIdx.x;
    const float* memB = mem + ((size_t)b * T_SZ + t0) * E_SZ;
    const float* al   = align + (size_t)b * T_SZ + t0;
    float2 acc = make_float2(0.f, 0.f);
    #pragma unroll 4
    for (int t = 0; t < CT; ++t) {
        const float w = al[t];
        float2 m = *(const float2*)(memB + (size_t)t * E_SZ + tid * 2);
        acc.x = fmaf(w, m.x, acc.x);
        acc.y = fmaf(w, m.y, acc.y);
    }
    atomicAdd(&ctx[b * E_SZ + tid * 2], acc.x);
    atomicAdd(&ctx[b * E_SZ + tid * 2 + 1], acc.y);
}

// ---------------------------------------------------------------------------
extern "C" void kernel_launch(void* const* d_in, const int* in_sizes, int n_in,
                              void* d_out, int out_size, void* d_ws, size_t ws_size,
                              hipStream_t stream) {
    const float* query  = (const float*)d_in[0];   // [32,1024]
    const float* memory = (const float*)d_in[1];   // [32,4096,512]
    // d_in[2] = attention_weights_cum — unused by the reference
    const float* Wq     = (const float*)d_in[3];   // [1024,128]
    const float* Wm     = (const float*)d_in[4];   // [512,128]
    const float* v      = (const float*)d_in[5];   // [128]

    float* ctx_out   = (float*)d_out;                    // [32,512]
    float* align_out = (float*)d_out + B_SZ * E_SZ;      // [32,4096]
    float* pq        = (float*)d_ws;                     // [32,128]

    k_pq<<<B_SZ, 128, 0, stream>>>(query, Wq, pq, ctx_out);
    k_scores<<<dim3(T_SZ / TT, B_SZ), 256, 0, stream>>>(memory, Wm, pq, v, align_out);
    k_softmax<<<B_SZ, 256, 0, stream>>>(align_out);
    k_ctx<<<dim3(T_SZ / CT, B_SZ), 256, 0, stream>>>(memory, align_out, ctx_out);
}

// Round 2
// 555.103 us; speedup vs baseline: 1.0721x; 1.0721x over previous
//
#include <hip/hip_runtime.h>
#include <hip/hip_bf16.h>
#include <math.h>

#define B_SZ 32
#define T_SZ 4096
#define A_SZ 128
#define E_SZ 512
#define D_SZ 1024

typedef __attribute__((ext_vector_type(8))) short short8;   // 8 bf16 (4 VGPRs)
typedef __attribute__((ext_vector_type(4))) float f32x4;

static __device__ __forceinline__ unsigned short f32_to_bf16_rne(float x) {
    unsigned int u = __float_as_uint(x);
    unsigned int r = (u + 0x7fffu + ((u >> 16) & 1u)) >> 16;
    return (unsigned short)r;
}
static __device__ __forceinline__ float bf16_to_f32(unsigned short h) {
    return __uint_as_float(((unsigned int)h) << 16);
}

// ---------------------------------------------------------------------------
// Prep: blocks 0..31  -> pq[b][a] = query[b]·Wq[:,a]; zero ctx row b
//       blocks 32..159 -> WmT hi/lo: WmT[a][e] = bf16split(Wm[e][a])
// grid: 160, block: 256
// ---------------------------------------------------------------------------
__global__ __launch_bounds__(256) void k_prep(const float* __restrict__ q,
                                              const float* __restrict__ Wq,
                                              const float* __restrict__ Wm,
                                              float* __restrict__ pq,
                                              unsigned short* __restrict__ WmTh,
                                              unsigned short* __restrict__ WmTl,
                                              float* __restrict__ ctx_out) {
    const int tid = threadIdx.x;
    if (blockIdx.x < 32) {
        const int b = blockIdx.x;
        __shared__ float ql[D_SZ];
        #pragma unroll
        for (int s = 0; s < D_SZ / 256; ++s)
            ql[s * 256 + tid] = q[b * D_SZ + s * 256 + tid];
        __syncthreads();
        if (tid < A_SZ) {
            const int a = tid;
            float acc = 0.f;
            #pragma unroll 8
            for (int d = 0; d < D_SZ; ++d)
                acc = fmaf(ql[d], Wq[d * A_SZ + a], acc);
            pq[b * A_SZ + a] = acc;
            // zero ctx row b: 512 floats = 128 threads * float4
            *(float4*)(ctx_out + (size_t)b * E_SZ + tid * 4) =
                make_float4(0.f, 0.f, 0.f, 0.f);
        }
    } else {
        const int a = blockIdx.x - 32;            // 0..127
        for (int e = tid; e < E_SZ; e += 256) {
            float x = Wm[(size_t)e * A_SZ + a];
            unsigned short h = f32_to_bf16_rne(x);
            float r = x - bf16_to_f32(h);
            unsigned short l = f32_to_bf16_rne(r);
            WmTh[(size_t)a * E_SZ + e] = h;
            WmTl[(size_t)a * E_SZ + e] = l;
        }
    }
}

// ---------------------------------------------------------------------------
// Scores via MFMA, split-precision bf16 (hh + hl + lh):
// scores[b][t] = sum_a tanh(pq[b][a] + (mem[b][t][:] @ Wm)[a]) * v[a]
// Block tile: 128 t x 128 a, K=E=512 in 8 chunks of 64.
// 4 waves; wave w owns t-rows [w*32, w*32+32): 2 m-frags x 8 n-frags of
// mfma_f32_16x16x32_bf16. A (memory) staged hi/lo in LDS; B (WmT) from L2.
// grid: (32, 32), block: 256
// ---------------------------------------------------------------------------
#define LDST 72   // LDS row stride in bf16 elems (64 + 8 pad -> 2-way banks only)

__global__ __launch_bounds__(256, 2) void k_scores_mfma(
    const float* __restrict__ mem,
    const unsigned short* __restrict__ WmTh,
    const unsigned short* __restrict__ WmTl,
    const float* __restrict__ pq,
    const float* __restrict__ v,
    float* __restrict__ scores) {
    __shared__ unsigned short Ah[128 * LDST];
    __shared__ unsigned short Al[128 * LDST];

    const int b = blockIdx.y;
    const int t0 = blockIdx.x * 128;
    const int tid = threadIdx.x;
    const int w = tid >> 6;
    const int lane = tid & 63;
    const int l16 = lane & 15;
    const int lk = lane >> 4;   // 0..3

    const float* memB = mem + ((size_t)b * T_SZ + t0) * E_SZ;

    float pqr[8], vr[8];
    #pragma unroll
    for (int n = 0; n < 8; ++n) {
        pqr[n] = pq[b * A_SZ + n * 16 + l16];
        vr[n]  = v[n * 16 + l16];
    }

    f32x4 acc[2][8];
    #pragma unroll
    for (int m = 0; m < 2; ++m)
        #pragma unroll
        for (int n = 0; n < 8; ++n)
            acc[m][n] = (f32x4){0.f, 0.f, 0.f, 0.f};

    for (int c = 0; c < 8; ++c) {
        const int e0 = c * 64;
        __syncthreads();
        // stage 128t x 64e chunk as hi/lo bf16
        #pragma unroll
        for (int s = 0; s < 8; ++s) {
            int idx = s * 256 + tid;
            int row = idx >> 4;
            int e4  = (idx & 15) << 2;
            float4 val = *(const float4*)(memB + (size_t)row * E_SZ + e0 + e4);
            float xs[4] = {val.x, val.y, val.z, val.w};
            unsigned int hp[2], lp[2];
            unsigned short h0 = f32_to_bf16_rne(xs[0]);
            unsigned short h1 = f32_to_bf16_rne(xs[1]);
            unsigned short h2 = f32_to_bf16_rne(xs[2]);
            unsigned short h3 = f32_to_bf16_rne(xs[3]);
            hp[0] = (unsigned int)h0 | ((unsigned int)h1 << 16);
            hp[1] = (unsigned int)h2 | ((unsigned int)h3 << 16);
            unsigned short l0 = f32_to_bf16_rne(xs[0] - bf16_to_f32(h0));
            unsigned short l1 = f32_to_bf16_rne(xs[1] - bf16_to_f32(h1));
            unsigned short l2 = f32_to_bf16_rne(xs[2] - bf16_to_f32(h2));
            unsigned short l3 = f32_to_bf16_rne(xs[3] - bf16_to_f32(h3));
            lp[0] = (unsigned int)l0 | ((unsigned int)l1 << 16);
            lp[1] = (unsigned int)l2 | ((unsigned int)l3 << 16);
            *(uint2*)&Ah[row * LDST + e4] = make_uint2(hp[0], hp[1]);
            *(uint2*)&Al[row * LDST + e4] = make_uint2(lp[0], lp[1]);
        }
        __syncthreads();

        #pragma unroll
        for (int kk = 0; kk < 2; ++kk) {
            short8 ah[2], al[2];
            #pragma unroll
            for (int m = 0; m < 2; ++m) {
                int row = w * 32 + m * 16 + l16;
                int off = row * LDST + kk * 32 + lk * 8;
                ah[m] = *(const short8*)&Ah[off];
                al[m] = *(const short8*)&Al[off];
            }
            const int eb = e0 + kk * 32 + lk * 8;
            #pragma unroll
            for (int n = 0; n < 8; ++n) {
                const int a = n * 16 + l16;
                short8 bh = *(const short8*)&WmTh[(size_t)a * E_SZ + eb];
                short8 bl = *(const short8*)&WmTl[(size_t)a * E_SZ + eb];
                acc[0][n] = __builtin_amdgcn_mfma_f32_16x16x32_bf16(ah[0], bh, acc[0][n], 0, 0, 0);
                acc[1][n] = __builtin_amdgcn_mfma_f32_16x16x32_bf16(ah[1], bh, acc[1][n], 0, 0, 0);
                acc[0][n] = __builtin_amdgcn_mfma_f32_16x16x32_bf16(al[0], bh, acc[0][n], 0, 0, 0);
                acc[1][n] = __builtin_amdgcn_mfma_f32_16x16x32_bf16(al[1], bh, acc[1][n], 0, 0, 0);
                acc[0][n] = __builtin_amdgcn_mfma_f32_16x16x32_bf16(ah[0], bl, acc[0][n], 0, 0, 0);
                acc[1][n] = __builtin_amdgcn_mfma_f32_16x16x32_bf16(ah[1], bl, acc[1][n], 0, 0, 0);
            }
        }
    }

    // epilogue: tanh + v-dot, reduce over a (cols = l16 lanes)
    #pragma unroll
    for (int m = 0; m < 2; ++m) {
        float part[4] = {0.f, 0.f, 0.f, 0.f};
        #pragma unroll
        for (int n = 0; n < 8; ++n)
            #pragma unroll
            for (int r = 0; r < 4; ++r)
                part[r] += tanhf(pqr[n] + acc[m][n][r]) * vr[n];
        #pragma unroll
        for (int r = 0; r < 4; ++r) {
            #pragma unroll
            for (int off = 1; off < 16; off <<= 1)
                part[r] += __shfl_xor(part[r], off);
        }
        if (l16 == 0) {
            const int t = t0 + w * 32 + m * 16 + lk * 4;
            #pragma unroll
            for (int r = 0; r < 4; ++r)
                scores[(size_t)b * T_SZ + t + r] = part[r];
        }
    }
}

// ---------------------------------------------------------------------------
// Softmax in-place over rows of scores [32][4096]. grid 32, block 256.
// ---------------------------------------------------------------------------
__global__ __launch_bounds__(256) void k_softmax(float* __restrict__ sc) {
    const int b = blockIdx.x;
    const int tid = threadIdx.x;
    float* row = sc + (size_t)b * T_SZ;

    float4 v4[4];
    float mx = -1e30f;
    #pragma unroll
    for (int s = 0; s < 4; ++s) {
        v4[s] = *(float4*)&row[(s * 256 + tid) * 4];
        mx = fmaxf(mx, fmaxf(fmaxf(v4[s].x, v4[s].y), fmaxf(v4[s].z, v4[s].w)));
    }
    #pragma unroll
    for (int off = 1; off < 64; off <<= 1)
        mx = fmaxf(mx, __shfl_xor(mx, off));
    __shared__ float redm[4], reds[4];
    const int wid = tid >> 6, lane = tid & 63;
    if (lane == 0) redm[wid] = mx;
    __syncthreads();
    mx = fmaxf(fmaxf(redm[0], redm[1]), fmaxf(redm[2], redm[3]));

    float sum = 0.f;
    #pragma unroll
    for (int s = 0; s < 4; ++s) {
        v4[s].x = __expf(v4[s].x - mx);
        v4[s].y = __expf(v4[s].y - mx);
        v4[s].z = __expf(v4[s].z - mx);
        v4[s].w = __expf(v4[s].w - mx);
        sum += v4[s].x + v4[s].y + v4[s].z + v4[s].w;
    }
    #pragma unroll
    for (int off = 1; off < 64; off <<= 1)
        sum += __shfl_xor(sum, off);
    if (lane == 0) reds[wid] = sum;
    __syncthreads();
    const float inv = 1.f / (reds[0] + reds[1] + reds[2] + reds[3]);
    #pragma unroll
    for (int s = 0; s < 4; ++s) {
        v4[s].x *= inv; v4[s].y *= inv; v4[s].z *= inv; v4[s].w *= inv;
        *(float4*)&row[(s * 256 + tid) * 4] = v4[s];
    }
}

// ---------------------------------------------------------------------------
// context[b][e] += sum_t align[b][t] * memory[b][t][e]
// grid: (32 t-chunks of 128, 32 b), block 256; alignments cached in LDS.
// ---------------------------------------------------------------------------
__global__ __launch_bounds__(256) void k_ctx(const float* __restrict__ mem,
                                             const float* __restrict__ align,
                                             float* __restrict__ ctx) {
    const int b  = blockIdx.y;
    const int t0 = blockIdx.x * 128;
    const int tid = threadIdx.x;
    __shared__ float al[128];
    if (tid < 128) al[tid] = align[(size_t)b * T_SZ + t0 + tid];
    __syncthreads();

    const float* memB = mem + ((size_t)b * T_SZ + t0) * E_SZ;
    const int e4 = (tid & 127) * 4;
    const int th = tid >> 7;           // 0/1
    float4 acc = make_float4(0.f, 0.f, 0.f, 0.f);
    #pragma unroll 4
    for (int t = th; t < 128; t += 2) {
        float4 m = *(const float4*)(memB + (size_t)t * E_SZ + e4);
        const float wgt = al[t];
        acc.x = fmaf(wgt, m.x, acc.x);
        acc.y = fmaf(wgt, m.y, acc.y);
        acc.z = fmaf(wgt, m.z, acc.z);
        acc.w = fmaf(wgt, m.w, acc.w);
    }
    float* c = ctx + (size_t)b * E_SZ + e4;
    atomicAdd(c + 0, acc.x);
    atomicAdd(c + 1, acc.y);
    atomicAdd(c + 2, acc.z);
    atomicAdd(c + 3, acc.w);
}

// ---------------------------------------------------------------------------
extern "C" void kernel_launch(void* const* d_in, const int* in_sizes, int n_in,
                              void* d_out, int out_size, void* d_ws, size_t ws_size,
                              hipStream_t stream) {
    const float* query  = (const float*)d_in[0];   // [32,1024]
    const float* memory = (const float*)d_in[1];   // [32,4096,512]
    const float* Wq     = (const float*)d_in[3];   // [1024,128]
    const float* Wm     = (const float*)d_in[4];   // [512,128]
    const float* v      = (const float*)d_in[5];   // [128]

    float* ctx_out   = (float*)d_out;                    // [32,512]
    float* align_out = (float*)d_out + B_SZ * E_SZ;      // [32,4096]

    char* ws = (char*)d_ws;
    float* pq            = (float*)ws;                         // 16 KB
    unsigned short* WmTh = (unsigned short*)(ws + 16 * 1024);  // 128 KB
    unsigned short* WmTl = (unsigned short*)(ws + 160 * 1024); // 128 KB

    k_prep<<<160, 256, 0, stream>>>(query, Wq, Wm, pq, WmTh, WmTl, ctx_out);
    k_scores_mfma<<<dim3(T_SZ / 128, B_SZ), 256, 0, stream>>>(memory, WmTh, WmTl, pq, v, align_out);
    k_softmax<<<B_SZ, 256, 0, stream>>>(align_out);
    k_ctx<<<dim3(T_SZ / 128, B_SZ), 256, 0, stream>>>(memory, align_out, ctx_out);
}

// Round 3
// 501.813 us; speedup vs baseline: 1.1860x; 1.1062x over previous
//
#include <hip/hip_runtime.h>
#include <hip/hip_bf16.h>
#include <math.h>

#define B_SZ 32
#define T_SZ 4096
#define A_SZ 128
#define E_SZ 512
#define D_SZ 1024
#define NCH  32          // t-chunks of 128

typedef __attribute__((ext_vector_type(8))) short short8;   // 8 bf16
typedef __attribute__((ext_vector_type(4))) float f32x4;

static __device__ __forceinline__ unsigned short f32_to_bf16_rne(float x) {
    unsigned int u = __float_as_uint(x);
    unsigned int r = (u + 0x7fffu + ((u >> 16) & 1u)) >> 16;
    return (unsigned short)r;
}
static __device__ __forceinline__ float bf16_to_f32(unsigned short h) {
    return __uint_as_float(((unsigned int)h) << 16);
}
static __device__ __forceinline__ float tanh_fast(float x) {
    float ax = fabsf(x);
    float e  = __expf(2.f * ax);
    float r  = 1.f - 2.f / (e + 1.f);
    return __builtin_copysignf(r, x);
}

// ---------------------------------------------------------------------------
// Prep: blocks 0..31  -> pq[b][a] = query[b]·Wq[:,a]
//       blocks 32..159 -> WmT hi/lo bf16 split: WmT[a][e] = split(Wm[e][a])
// ---------------------------------------------------------------------------
__global__ __launch_bounds__(256) void k_prep(const float* __restrict__ q,
                                              const float* __restrict__ Wq,
                                              const float* __restrict__ Wm,
                                              float* __restrict__ pq,
                                              unsigned short* __restrict__ WmTh,
                                              unsigned short* __restrict__ WmTl) {
    const int tid = threadIdx.x;
    if (blockIdx.x < 32) {
        const int b = blockIdx.x;
        __shared__ float ql[D_SZ];
        #pragma unroll
        for (int s = 0; s < D_SZ / 256; ++s)
            ql[s * 256 + tid] = q[b * D_SZ + s * 256 + tid];
        __syncthreads();
        if (tid < A_SZ) {
            const int a = tid;
            float acc = 0.f;
            #pragma unroll 8
            for (int d = 0; d < D_SZ; ++d)
                acc = fmaf(ql[d], Wq[d * A_SZ + a], acc);
            pq[b * A_SZ + a] = acc;
        }
    } else {
        const int a = blockIdx.x - 32;            // 0..127
        for (int e = tid; e < E_SZ; e += 256) {
            float x = Wm[(size_t)e * A_SZ + a];
            unsigned short h = f32_to_bf16_rne(x);
            float r = x - bf16_to_f32(h);
            unsigned short l = f32_to_bf16_rne(r);
            WmTh[(size_t)a * E_SZ + e] = h;
            WmTl[(size_t)a * E_SZ + e] = l;
        }
    }
}

// ---------------------------------------------------------------------------
// Fused: scores (split-bf16 MFMA, hh+hl+lh) -> tanh·v -> chunk-local softmax
// stats -> chunk-local weighted context partial.
// Block tile: 128 t x 128 a, K-chunk = 32 (one MFMA K-step), 16 chunks.
// LDS ~39.9 KB -> 4 blocks/CU. A stride 36 (conflict-free), B stride 40
// (2-way = free).
// grid: (NCH=32, B=32), block 256 (4 waves; wave w owns t-rows w*32..w*32+31)
// ---------------------------------------------------------------------------
#define AST 36
#define BST 40

__global__ __launch_bounds__(256, 4) void k_fused(
    const float* __restrict__ mem,
    const unsigned short* __restrict__ WmTh,
    const unsigned short* __restrict__ WmTl,
    const float* __restrict__ pq,
    const float* __restrict__ v,
    float* __restrict__ scores_raw,    // [B][T] raw scores (d_out align region)
    float* __restrict__ ctx_part,      // [NCH][B][E]
    float* __restrict__ mZ)            // [B][NCH][2] = {chunk max, chunk expsum}
{
    __shared__ unsigned short Ah[128 * AST];
    __shared__ unsigned short Al[128 * AST];
    __shared__ unsigned short Bh[128 * BST];
    __shared__ unsigned short Bl[128 * BST];
    __shared__ float sc[128];
    __shared__ float wbuf[128];
    __shared__ float red[8];

    const int cb = blockIdx.x;
    const int b  = blockIdx.y;
    const int t0 = cb * 128;
    const int tid = threadIdx.x;
    const int w = tid >> 6;
    const int lane = tid & 63;
    const int l16 = lane & 15;
    const int lk = lane >> 4;   // 0..3

    const float* memB = mem + ((size_t)b * T_SZ + t0) * E_SZ;

    float pqr[8], vr[8];
    #pragma unroll
    for (int n = 0; n < 8; ++n) {
        pqr[n] = pq[b * A_SZ + n * 16 + l16];
        vr[n]  = v[n * 16 + l16];
    }

    f32x4 acc[2][8];
    #pragma unroll
    for (int m = 0; m < 2; ++m)
        #pragma unroll
        for (int n = 0; n < 8; ++n)
            acc[m][n] = (f32x4){0.f, 0.f, 0.f, 0.f};

    for (int c = 0; c < 16; ++c) {
        const int e0 = c * 32;
        __syncthreads();
        // stage A: 128t x 32e f32 -> hi/lo bf16 (4 float4 per thread)
        #pragma unroll
        for (int s = 0; s < 4; ++s) {
            int idx = s * 256 + tid;
            int row = idx >> 3;            // 0..127
            int e4  = (idx & 7) << 2;      // 0..28
            float4 val = *(const float4*)(memB + (size_t)row * E_SZ + e0 + e4);
            float xs[4] = {val.x, val.y, val.z, val.w};
            unsigned short h[4], l[4];
            #pragma unroll
            for (int k = 0; k < 4; ++k) {
                h[k] = f32_to_bf16_rne(xs[k]);
                l[k] = f32_to_bf16_rne(xs[k] - bf16_to_f32(h[k]));
            }
            unsigned int hp0 = (unsigned int)h[0] | ((unsigned int)h[1] << 16);
            unsigned int hp1 = (unsigned int)h[2] | ((unsigned int)h[3] << 16);
            unsigned int lp0 = (unsigned int)l[0] | ((unsigned int)l[1] << 16);
            unsigned int lp1 = (unsigned int)l[2] | ((unsigned int)l[3] << 16);
            *(uint2*)&Ah[row * AST + e4] = make_uint2(hp0, hp1);
            *(uint2*)&Al[row * AST + e4] = make_uint2(lp0, lp1);
        }
        // stage B: 128a x 32e hi/lo bf16 (2 x 16B per thread per array)
        #pragma unroll
        for (int s = 0; s < 2; ++s) {
            int idx = s * 256 + tid;       // 0..511
            int a   = idx >> 2;            // 0..127
            int es  = (idx & 3) << 3;      // 0,8,16,24
            *(short8*)&Bh[a * BST + es] =
                *(const short8*)&WmTh[(size_t)a * E_SZ + e0 + es];
            *(short8*)&Bl[a * BST + es] =
                *(const short8*)&WmTl[(size_t)a * E_SZ + e0 + es];
        }
        __syncthreads();

        short8 ah[2], al[2];
        #pragma unroll
        for (int m = 0; m < 2; ++m) {
            int off = (w * 32 + m * 16 + l16) * AST + lk * 8;
            ah[m] = *(const short8*)&Ah[off];
            al[m] = *(const short8*)&Al[off];
        }
        #pragma unroll
        for (int n = 0; n < 8; ++n) {
            int boff = (n * 16 + l16) * BST + lk * 8;
            short8 bh = *(const short8*)&Bh[boff];
            short8 bl = *(const short8*)&Bl[boff];
            acc[0][n] = __builtin_amdgcn_mfma_f32_16x16x32_bf16(ah[0], bh, acc[0][n], 0, 0, 0);
            acc[1][n] = __builtin_amdgcn_mfma_f32_16x16x32_bf16(ah[1], bh, acc[1][n], 0, 0, 0);
            acc[0][n] = __builtin_amdgcn_mfma_f32_16x16x32_bf16(al[0], bh, acc[0][n], 0, 0, 0);
            acc[1][n] = __builtin_amdgcn_mfma_f32_16x16x32_bf16(al[1], bh, acc[1][n], 0, 0, 0);
            acc[0][n] = __builtin_amdgcn_mfma_f32_16x16x32_bf16(ah[0], bl, acc[0][n], 0, 0, 0);
            acc[1][n] = __builtin_amdgcn_mfma_f32_16x16x32_bf16(ah[1], bl, acc[1][n], 0, 0, 0);
        }
    }

    // epilogue: tanh + v-dot, reduce over a-cols (l16 lanes)
    #pragma unroll
    for (int m = 0; m < 2; ++m) {
        float part[4] = {0.f, 0.f, 0.f, 0.f};
        #pragma unroll
        for (int n = 0; n < 8; ++n)
            #pragma unroll
            for (int r = 0; r < 4; ++r)
                part[r] += tanh_fast(pqr[n] + acc[m][n][r]) * vr[n];
        #pragma unroll
        for (int r = 0; r < 4; ++r) {
            #pragma unroll
            for (int off = 1; off < 16; off <<= 1)
                part[r] += __shfl_xor(part[r], off);
        }
        if (l16 == 0) {
            const int tl = w * 32 + m * 16 + lk * 4;
            #pragma unroll
            for (int r = 0; r < 4; ++r)
                sc[tl + r] = part[r];
        }
    }
    __syncthreads();

    // chunk max over 128 scores
    float mv = sc[tid & 127];
    #pragma unroll
    for (int off = 1; off < 64; off <<= 1)
        mv = fmaxf(mv, __shfl_xor(mv, off));
    if (lane == 0) red[w] = mv;
    __syncthreads();
    const float Mc = fmaxf(fmaxf(red[0], red[1]), fmaxf(red[2], red[3]));

    // weights + chunk exp-sum; also dump raw scores
    float wv = 0.f;
    if (tid < 128) {
        wv = __expf(sc[tid] - Mc);
        wbuf[tid] = wv;
        scores_raw[(size_t)b * T_SZ + t0 + tid] = sc[tid];
    }
    float sv = wv;
    #pragma unroll
    for (int off = 1; off < 64; off <<= 1)
        sv += __shfl_xor(sv, off);
    if (lane == 0) red[4 + w] = sv;
    __syncthreads();
    if (tid == 0) {
        const float Zc = red[4] + red[5];
        mZ[(b * NCH + cb) * 2 + 0] = Mc;
        mZ[(b * NCH + cb) * 2 + 1] = Zc;
    }

    // chunk-local PV: ctx_c[e] = sum_t exp(s_t - Mc) * mem[t][e]  (L2/L3-hot)
    const int e2 = tid * 2;
    float2 a2 = make_float2(0.f, 0.f);
    #pragma unroll 8
    for (int t = 0; t < 128; ++t) {
        float2 mm = *(const float2*)(memB + (size_t)t * E_SZ + e2);
        const float wt = wbuf[t];
        a2.x = fmaf(wt, mm.x, a2.x);
        a2.y = fmaf(wt, mm.y, a2.y);
    }
    *(float2*)(ctx_part + ((size_t)cb * B_SZ + b) * E_SZ + e2) = a2;
}

// ---------------------------------------------------------------------------
// Combine: per b, merge 32 chunk partials; normalize ctx and alignments.
// grid: (32), block 256
// ---------------------------------------------------------------------------
__global__ __launch_bounds__(256) void k_combine(
    const float* __restrict__ ctx_part,
    const float* __restrict__ mZ,
    float* __restrict__ ctx,       // [B][E]
    float* __restrict__ align)     // [B][T] in-place raw -> normalized
{
    const int b = blockIdx.x;
    const int tid = threadIdx.x;
    float mc[NCH], zc[NCH], ec[NCH];
    float M = -1e30f;
    #pragma unroll
    for (int c = 0; c < NCH; ++c) {
        float2 p = *(const float2*)(mZ + (b * NCH + c) * 2);
        mc[c] = p.x; zc[c] = p.y;
        M = fmaxf(M, p.x);
    }
    float Z = 0.f;
    #pragma unroll
    for (int c = 0; c < NCH; ++c) {
        ec[c] = __expf(mc[c] - M);
        Z = fmaf(zc[c], ec[c], Z);
    }
    const float invZ = 1.f / Z;

    const int e2 = tid * 2;
    float2 a2 = make_float2(0.f, 0.f);
    #pragma unroll
    for (int c = 0; c < NCH; ++c) {
        float2 p = *(const float2*)(ctx_part + ((size_t)c * B_SZ + b) * E_SZ + e2);
        a2.x = fmaf(p.x, ec[c], a2.x);
        a2.y = fmaf(p.y, ec[c], a2.y);
    }
    float2 outv = make_float2(a2.x * invZ, a2.y * invZ);
    *(float2*)(ctx + (size_t)b * E_SZ + e2) = outv;

    float* row = align + (size_t)b * T_SZ;
    #pragma unroll
    for (int s = 0; s < 4; ++s) {
        float4 vv = *(float4*)&row[(s * 256 + tid) * 4];
        vv.x = __expf(vv.x - M) * invZ;
        vv.y = __expf(vv.y - M) * invZ;
        vv.z = __expf(vv.z - M) * invZ;
        vv.w = __expf(vv.w - M) * invZ;
        *(float4*)&row[(s * 256 + tid) * 4] = vv;
    }
}

// ---------------------------------------------------------------------------
extern "C" void kernel_launch(void* const* d_in, const int* in_sizes, int n_in,
                              void* d_out, int out_size, void* d_ws, size_t ws_size,
                              hipStream_t stream) {
    const float* query  = (const float*)d_in[0];   // [32,1024]
    const float* memory = (const float*)d_in[1];   // [32,4096,512]
    const float* Wq     = (const float*)d_in[3];   // [1024,128]
    const float* Wm     = (const float*)d_in[4];   // [512,128]
    const float* v      = (const float*)d_in[5];   // [128]

    float* ctx_out   = (float*)d_out;                    // [32,512]
    float* align_out = (float*)d_out + B_SZ * E_SZ;      // [32,4096]

    char* ws = (char*)d_ws;
    float*          pq       = (float*)(ws + 0);               // 16 KB
    unsigned short* WmTh     = (unsigned short*)(ws + 16384);  // 128 KB
    unsigned short* WmTl     = (unsigned short*)(ws + 147456); // 128 KB
    float*          mZ       = (float*)(ws + 278528);          // 8 KB
    float*          ctx_part = (float*)(ws + 286720);          // 2 MB

    k_prep<<<160, 256, 0, stream>>>(query, Wq, Wm, pq, WmTh, WmTl);
    k_fused<<<dim3(NCH, B_SZ), 256, 0, stream>>>(memory, WmTh, WmTl, pq, v,
                                                 align_out, ctx_part, mZ);
    k_combine<<<B_SZ, 256, 0, stream>>>(ctx_part, mZ, ctx_out, align_out);
}

// Round 4
// 468.283 us; speedup vs baseline: 1.2709x; 1.0716x over previous
//
#include <hip/hip_runtime.h>
#include <hip/hip_bf16.h>
#include <math.h>

#define B_SZ 32
#define T_SZ 4096
#define A_SZ 128
#define E_SZ 512
#define D_SZ 1024
#define NCH  32          // t-chunks of 128

typedef __attribute__((ext_vector_type(8))) short short8;   // 8 bf16
typedef __attribute__((ext_vector_type(4))) float f32x4;

static __device__ __forceinline__ unsigned short f32_to_bf16_rne(float x) {
    unsigned int u = __float_as_uint(x);
    unsigned int r = (u + 0x7fffu + ((u >> 16) & 1u)) >> 16;
    return (unsigned short)r;
}
static __device__ __forceinline__ float bf16_to_f32(unsigned short h) {
    return __uint_as_float(((unsigned int)h) << 16);
}
static __device__ __forceinline__ float tanh_fast(float x) {
    float ax = fabsf(x);
    float e  = __expf(2.f * ax);
    float r  = 1.f - 2.f / (e + 1.f);
    return __builtin_copysignf(r, x);
}

// ---------------------------------------------------------------------------
// Prep: blocks 0..31  -> pq[b][a] = query[b]·Wq[:,a]
//       blocks 32..159 -> WmT hi/lo bf16 split: WmT[a][e] = split(Wm[e][a])
// ---------------------------------------------------------------------------
__global__ __launch_bounds__(256) void k_prep(const float* __restrict__ q,
                                              const float* __restrict__ Wq,
                                              const float* __restrict__ Wm,
                                              float* __restrict__ pq,
                                              unsigned short* __restrict__ WmTh,
                                              unsigned short* __restrict__ WmTl) {
    const int tid = threadIdx.x;
    if (blockIdx.x < 32) {
        const int b = blockIdx.x;
        __shared__ float ql[D_SZ];
        #pragma unroll
        for (int s = 0; s < D_SZ / 256; ++s)
            ql[s * 256 + tid] = q[b * D_SZ + s * 256 + tid];
        __syncthreads();
        if (tid < A_SZ) {
            const int a = tid;
            float acc = 0.f;
            #pragma unroll 8
            for (int d = 0; d < D_SZ; ++d)
                acc = fmaf(ql[d], Wq[d * A_SZ + a], acc);
            pq[b * A_SZ + a] = acc;
        }
    } else {
        const int a = blockIdx.x - 32;            // 0..127
        for (int e = tid; e < E_SZ; e += 256) {
            float x = Wm[(size_t)e * A_SZ + a];
            unsigned short h = f32_to_bf16_rne(x);
            float r = x - bf16_to_f32(h);
            unsigned short l = f32_to_bf16_rne(r);
            WmTh[(size_t)a * E_SZ + e] = h;
            WmTl[(size_t)a * E_SZ + e] = l;
        }
    }
}

// ---------------------------------------------------------------------------
// Fused: scores (split-bf16 MFMA, hh+hl+lh) -> tanh·v -> chunk softmax stats
// -> chunk-local weighted context partial.
// Pipelined: A-tile prefetched 1 chunk ahead through registers (T14);
// K-chunk order rotated per block to decorrelate HBM demand phases.
// grid: (NCH=32, B=32), block 256 (4 waves).
// ---------------------------------------------------------------------------
#define AST 36
#define BST 40

__global__ __launch_bounds__(256, 4) void k_fused(
    const float* __restrict__ mem,
    const unsigned short* __restrict__ WmTh,
    const unsigned short* __restrict__ WmTl,
    const float* __restrict__ pq,
    const float* __restrict__ v,
    float* __restrict__ scores_raw,    // [B][T] raw scores (d_out align region)
    float* __restrict__ ctx_part,      // [NCH][B][E]
    float* __restrict__ mZ)            // [B][NCH][2] = {chunk max, chunk expsum}
{
    __shared__ unsigned short Ah[128 * AST];
    __shared__ unsigned short Al[128 * AST];
    __shared__ unsigned short Bh[128 * BST];
    __shared__ unsigned short Bl[128 * BST];
    __shared__ float sc[128];
    __shared__ float wbuf[128];
    __shared__ float red[8];

    const int cb = blockIdx.x;
    const int b  = blockIdx.y;
    const int t0 = cb * 128;
    const int tid = threadIdx.x;
    const int w = tid >> 6;
    const int lane = tid & 63;
    const int l16 = lane & 15;
    const int lk = lane >> 4;   // 0..3
    const int rot = (cb + b) & 15;

    const float* memB = mem + ((size_t)b * T_SZ + t0) * E_SZ;

    // per-thread staging coords (A): 4 slices, row = idx>>3, e4 = (idx&7)*4
    const int ar0 = tid >> 3;           // row for s=0 (rows advance by 32/s)
    const int ae4 = (tid & 7) << 2;

    f32x4 acc[2][8];
    #pragma unroll
    for (int m = 0; m < 2; ++m)
        #pragma unroll
        for (int n = 0; n < 8; ++n)
            acc[m][n] = (f32x4){0.f, 0.f, 0.f, 0.f};

    // prologue: load A chunk (rot) into regs
    float4 ra[4];
    {
        const int e0 = rot * 32;
        #pragma unroll
        for (int s = 0; s < 4; ++s)
            ra[s] = *(const float4*)(memB + (size_t)(ar0 + s * 32) * E_SZ + e0 + ae4);
    }

    for (int c = 0; c < 16; ++c) {
        const int cc = (c + rot) & 15;
        const int e0 = cc * 32;

        // (1) B stage: L2 -> LDS (issued first so its wait is vmcnt-counted
        //     BEFORE the A-prefetch below, keeping the prefetch in flight)
        short8 rbh[2], rbl[2];
        #pragma unroll
        for (int s = 0; s < 2; ++s) {
            int idx = s * 256 + tid;
            int a   = idx >> 2;
            int es  = (idx & 3) << 3;
            rbh[s] = *(const short8*)&WmTh[(size_t)a * E_SZ + e0 + es];
            rbl[s] = *(const short8*)&WmTl[(size_t)a * E_SZ + e0 + es];
        }

        // (2) issue next A chunk loads (non-blocking, consumed next iter)
        float4 rn[4];
        if (c < 15) {
            const int en = ((c + 1 + rot) & 15) * 32;
            #pragma unroll
            for (int s = 0; s < 4; ++s)
                rn[s] = *(const float4*)(memB + (size_t)(ar0 + s * 32) * E_SZ + en + ae4);
        }

        // (3) B regs -> LDS
        #pragma unroll
        for (int s = 0; s < 2; ++s) {
            int idx = s * 256 + tid;
            int a   = idx >> 2;
            int es  = (idx & 3) << 3;
            *(short8*)&Bh[a * BST + es] = rbh[s];
            *(short8*)&Bl[a * BST + es] = rbl[s];
        }

        // (4) convert current A regs -> hi/lo bf16 -> LDS
        #pragma unroll
        for (int s = 0; s < 4; ++s) {
            const int row = ar0 + s * 32;
            float xs[4] = {ra[s].x, ra[s].y, ra[s].z, ra[s].w};
            unsigned short h[4], l[4];
            #pragma unroll
            for (int k = 0; k < 4; ++k) {
                h[k] = f32_to_bf16_rne(xs[k]);
                l[k] = f32_to_bf16_rne(xs[k] - bf16_to_f32(h[k]));
            }
            unsigned int hp0 = (unsigned int)h[0] | ((unsigned int)h[1] << 16);
            unsigned int hp1 = (unsigned int)h[2] | ((unsigned int)h[3] << 16);
            unsigned int lp0 = (unsigned int)l[0] | ((unsigned int)l[1] << 16);
            unsigned int lp1 = (unsigned int)l[2] | ((unsigned int)l[3] << 16);
            *(uint2*)&Ah[row * AST + ae4] = make_uint2(hp0, hp1);
            *(uint2*)&Al[row * AST + ae4] = make_uint2(lp0, lp1);
        }
        __syncthreads();

        // (5) MFMA on staged chunk
        short8 ah[2], al[2];
        #pragma unroll
        for (int m = 0; m < 2; ++m) {
            int off = (w * 32 + m * 16 + l16) * AST + lk * 8;
            ah[m] = *(const short8*)&Ah[off];
            al[m] = *(const short8*)&Al[off];
        }
        #pragma unroll
        for (int n = 0; n < 8; ++n) {
            int boff = (n * 16 + l16) * BST + lk * 8;
            short8 bh = *(const short8*)&Bh[boff];
            short8 bl = *(const short8*)&Bl[boff];
            acc[0][n] = __builtin_amdgcn_mfma_f32_16x16x32_bf16(ah[0], bh, acc[0][n], 0, 0, 0);
            acc[1][n] = __builtin_amdgcn_mfma_f32_16x16x32_bf16(ah[1], bh, acc[1][n], 0, 0, 0);
            acc[0][n] = __builtin_amdgcn_mfma_f32_16x16x32_bf16(al[0], bh, acc[0][n], 0, 0, 0);
            acc[1][n] = __builtin_amdgcn_mfma_f32_16x16x32_bf16(al[1], bh, acc[1][n], 0, 0, 0);
            acc[0][n] = __builtin_amdgcn_mfma_f32_16x16x32_bf16(ah[0], bl, acc[0][n], 0, 0, 0);
            acc[1][n] = __builtin_amdgcn_mfma_f32_16x16x32_bf16(ah[1], bl, acc[1][n], 0, 0, 0);
        }
        __syncthreads();

        if (c < 15) {
            #pragma unroll
            for (int s = 0; s < 4; ++s) ra[s] = rn[s];
        }
    }

    // epilogue: tanh + v-dot, reduce over a-cols (l16 lanes)
    float pqr[8], vr[8];
    #pragma unroll
    for (int n = 0; n < 8; ++n) {
        pqr[n] = pq[b * A_SZ + n * 16 + l16];
        vr[n]  = v[n * 16 + l16];
    }
    #pragma unroll
    for (int m = 0; m < 2; ++m) {
        float part[4] = {0.f, 0.f, 0.f, 0.f};
        #pragma unroll
        for (int n = 0; n < 8; ++n)
            #pragma unroll
            for (int r = 0; r < 4; ++r)
                part[r] += tanh_fast(pqr[n] + acc[m][n][r]) * vr[n];
        #pragma unroll
        for (int r = 0; r < 4; ++r) {
            #pragma unroll
            for (int off = 1; off < 16; off <<= 1)
                part[r] += __shfl_xor(part[r], off);
        }
        if (l16 == 0) {
            const int tl = w * 32 + m * 16 + lk * 4;
            #pragma unroll
            for (int r = 0; r < 4; ++r)
                sc[tl + r] = part[r];
        }
    }
    __syncthreads();

    // chunk max over 128 scores
    float mv = sc[tid & 127];
    #pragma unroll
    for (int off = 1; off < 64; off <<= 1)
        mv = fmaxf(mv, __shfl_xor(mv, off));
    if (lane == 0) red[w] = mv;
    __syncthreads();
    const float Mc = fmaxf(fmaxf(red[0], red[1]), fmaxf(red[2], red[3]));

    // weights + chunk exp-sum; also dump raw scores
    float wv = 0.f;
    if (tid < 128) {
        wv = __expf(sc[tid] - Mc);
        wbuf[tid] = wv;
        scores_raw[(size_t)b * T_SZ + t0 + tid] = sc[tid];
    }
    float sv = wv;
    #pragma unroll
    for (int off = 1; off < 64; off <<= 1)
        sv += __shfl_xor(sv, off);
    if (lane == 0) red[4 + w] = sv;
    __syncthreads();
    if (tid == 0) {
        const float Zc = red[4] + red[5];
        mZ[(b * NCH + cb) * 2 + 0] = Mc;
        mZ[(b * NCH + cb) * 2 + 1] = Zc;
    }

    // chunk-local PV: ctx_c[e] = sum_t exp(s_t - Mc) * mem[t][e]  (L2/L3-hot)
    const int e2 = tid * 2;
    float2 a2 = make_float2(0.f, 0.f);
    #pragma unroll 8
    for (int t = 0; t < 128; ++t) {
        float2 mm = *(const float2*)(memB + (size_t)t * E_SZ + e2);
        const float wt = wbuf[t];
        a2.x = fmaf(wt, mm.x, a2.x);
        a2.y = fmaf(wt, mm.y, a2.y);
    }
    *(float2*)(ctx_part + ((size_t)cb * B_SZ + b) * E_SZ + e2) = a2;
}

// ---------------------------------------------------------------------------
// Combine: per b, merge 32 chunk partials; normalize ctx and alignments.
// grid: (32), block 256
// ---------------------------------------------------------------------------
__global__ __launch_bounds__(256) void k_combine(
    const float* __restrict__ ctx_part,
    const float* __restrict__ mZ,
    float* __restrict__ ctx,       // [B][E]
    float* __restrict__ align)     // [B][T] in-place raw -> normalized
{
    const int b = blockIdx.x;
    const int tid = threadIdx.x;
    float mc[NCH], zc[NCH], ec[NCH];
    float M = -1e30f;
    #pragma unroll
    for (int c = 0; c < NCH; ++c) {
        float2 p = *(const float2*)(mZ + (b * NCH + c) * 2);
        mc[c] = p.x; zc[c] = p.y;
        M = fmaxf(M, p.x);
    }
    float Z = 0.f;
    #pragma unroll
    for (int c = 0; c < NCH; ++c) {
        ec[c] = __expf(mc[c] - M);
        Z = fmaf(zc[c], ec[c], Z);
    }
    const float invZ = 1.f / Z;

    const int e2 = tid * 2;
    float2 a2 = make_float2(0.f, 0.f);
    #pragma unroll
    for (int c = 0; c < NCH; ++c) {
        float2 p = *(const float2*)(ctx_part + ((size_t)c * B_SZ + b) * E_SZ + e2);
        a2.x = fmaf(p.x, ec[c], a2.x);
        a2.y = fmaf(p.y, ec[c], a2.y);
    }
    float2 outv = make_float2(a2.x * invZ, a2.y * invZ);
    *(float2*)(ctx + (size_t)b * E_SZ + e2) = outv;

    float* row = align + (size_t)b * T_SZ;
    #pragma unroll
    for (int s = 0; s < 4; ++s) {
        float4 vv = *(float4*)&row[(s * 256 + tid) * 4];
        vv.x = __expf(vv.x - M) * invZ;
        vv.y = __expf(vv.y - M) * invZ;
        vv.z = __expf(vv.z - M) * invZ;
        vv.w = __expf(vv.w - M) * invZ;
        *(float4*)&row[(s * 256 + tid) * 4] = vv;
    }
}

// ---------------------------------------------------------------------------
extern "C" void kernel_launch(void* const* d_in, const int* in_sizes, int n_in,
                              void* d_out, int out_size, void* d_ws, size_t ws_size,
                              hipStream_t stream) {
    const float* query  = (const float*)d_in[0];   // [32,1024]
    const float* memory = (const float*)d_in[1];   // [32,4096,512]
    const float* Wq     = (const float*)d_in[3];   // [1024,128]
    const float* Wm     = (const float*)d_in[4];   // [512,128]
    const float* v      = (const float*)d_in[5];   // [128]

    float* ctx_out   = (float*)d_out;                    // [32,512]
    float* align_out = (float*)d_out + B_SZ * E_SZ;      // [32,4096]

    char* ws = (char*)d_ws;
    float*          pq       = (float*)(ws + 0);               // 16 KB
    unsigned short* WmTh     = (unsigned short*)(ws + 16384);  // 128 KB
    unsigned short* WmTl     = (unsigned short*)(ws + 147456); // 128 KB
    float*          mZ       = (float*)(ws + 278528);          // 8 KB
    float*          ctx_part = (float*)(ws + 286720);          // 2 MB

    k_prep<<<160, 256, 0, stream>>>(query, Wq, Wm, pq, WmTh, WmTl);
    k_fused<<<dim3(NCH, B_SZ), 256, 0, stream>>>(memory, WmTh, WmTl, pq, v,
                                                 align_out, ctx_part, mZ);
    k_combine<<<B_SZ, 256, 0, stream>>>(ctx_part, mZ, ctx_out, align_out);
}